// Round 21
// baseline (249.216 us; speedup 1.0000x reference)
//
#include <hip/hip_runtime.h>
#include <hip/hip_bf16.h>

typedef float  f32x4 __attribute__((ext_vector_type(4)));
typedef short  s16x8 __attribute__((ext_vector_type(8)));

#define NB   1024
#define SEQ  64
#define DIM  512
#define NH   8
#define SCALE 0.044194173824159216f

// per-wave tail-tile slot: XOR swizzle keeps 8-aligned vector reads contiguous
// and spreads fixed-column accesses across 8 bank groups.
#define TS(r, c) ((r) * 64 + ((c) ^ (((r) & 7) << 3)))

// Compile-time scheduling fence: REQUIRED between a wave's T-tile writes and
// its cross-lane reads of the same tile. The compiler's per-thread alias
// analysis may hoist reads above other-lane writes (R20: qb read stale data
// -> Output 1 absmax 0.468; guide rule #18 hazard class). HW executes a
// wave's DS ops in order, so a compile-time fence suffices.
#define LDS_FENCE() __builtin_amdgcn_sched_barrier(0)

// round-half-up f32->bf16: 2 VALU ops
static __device__ __forceinline__ unsigned short f2bf(float f) {
    unsigned u = __builtin_bit_cast(unsigned, f);
    return (unsigned short)((u + 0x8000u) >> 16);
}

static __device__ __forceinline__ f32x4 mma(s16x8 a, s16x8 b, f32x4 c) {
    return __builtin_amdgcn_mfma_f32_16x16x32_bf16(a, b, c, 0, 0, 0);
}

static __device__ __forceinline__ s16x8 cvt2(float4 a, float4 b) {
    s16x8 x;
    x[0] = (short)f2bf(a.x); x[1] = (short)f2bf(a.y);
    x[2] = (short)f2bf(a.z); x[3] = (short)f2bf(a.w);
    x[4] = (short)f2bf(b.x); x[5] = (short)f2bf(b.y);
    x[6] = (short)f2bf(b.z); x[7] = (short)f2bf(b.w);
    return x;
}

// Pre-kernel: Wq, Wc (f32 [512][512] row-major [k][n]) -> bf16 B-fragment order.
__global__ __launch_bounds__(256) void prep_weights(
    const float* __restrict__ Wq, const float* __restrict__ Wc,
    unsigned short* __restrict__ wf)
{
    int gid  = blockIdx.x * 256 + threadIdx.x;   // 0..65535
    int m    = gid >> 15;
    int tile = (gid >> 10) & 31;
    int ks   = (gid >> 6) & 15;
    int lane = gid & 63;
    const float* W = m ? Wc : Wq;
    int col = tile * 16 + (lane & 15);
    int k0  = ks * 32 + (lane >> 4) * 8;
    unsigned short* dst = wf + (size_t)gid * 8;
#pragma unroll
    for (int j = 0; j < 8; ++j)
        dst[j] = f2bf(W[(size_t)(k0 + j) * DIM + col]);
}

// ====================== Fused kernel: one block = one batch b ======================
// R21 = R20 (single 64 KB LDS region, serially reused) + LDS_FENCE at the
// four tail write->cross-lane-read handoffs (the R20 correctness bug).
// Goal: 64 KB LDS -> TWO 8-wave blocks/CU (if unified regs <= 128, as R13
// measured) -> cross-block overlap of read-stall/store-drain with compute.
// FAILED-mechanism ledger (counter-proven; do not revisit): min-waves
// launch_bounds clamp (R2/R7), multi-block with >128 unified (R6/8/9/11/14),
// reg-held prefetch across tail (R15/R18 spills), global_load_lds across
// barriers (R16 drain), intra-basic-block load staggering (R17 neutral),
// unfenced cross-lane tail reads (R20 stale-data).
__global__ __launch_bounds__(512) void fused_s(
    const float* __restrict__ query,
    const float* __restrict__ context,
    const float* __restrict__ bq,
    const float* __restrict__ bc,
    const unsigned short* __restrict__ wf,
    float* __restrict__ out)
{
    __shared__ unsigned short S[32768];   // 64 KB: stage buffer == 8 tail tiles

    const int tid  = threadIdx.x;
    const int lane = tid & 63;
    const int wv   = tid >> 6;          // wave id = head
    const int l15  = lane & 15;
    const int l4   = lane >> 4;
    const int b    = blockIdx.x;

    const float* gq = query   + (size_t)b * SEQ * DIM;
    const float* gc = context + (size_t)b * SEQ * DIM;

    const int row = tid >> 3;
    const int cw  = tid & 7;
    const int wsb = (cw >> 2) * 256 + (cw & 3) * 64 + row;
    const float* csrc = gc + (size_t)row * DIM + cw * 8;
    const float* qsrc = gq + (size_t)row * DIM + cw * 8;

    unsigned short* Tw = S + wv * 4096;  // this wave's 64x64 XOR tile
    const f32x4 fz = {0.f, 0.f, 0.f, 0.f};
    f32x4 acc[4][4];

#define STAGE(SRC)                                                             \
    {                                                                          \
        float4 ld[16];                                                         \
        _Pragma("unroll")                                                      \
        for (int p = 0; p < 8; ++p) {                                          \
            ld[2 * p]     = *(const float4*)((SRC) + p * 64);                  \
            ld[2 * p + 1] = *(const float4*)((SRC) + p * 64 + 4);              \
        }                                                                      \
        _Pragma("unroll")                                                      \
        for (int p = 0; p < 8; ++p)                                            \
            *(s16x8*)&S[((p * 512 + wsb) ^ cw) * 8] =                          \
                cvt2(ld[2 * p], ld[2 * p + 1]);                                \
    }

#define GEMM16(WFM)                                                            \
    {                                                                          \
        _Pragma("unroll")                                                      \
        for (int ks = 0; ks < 16; ++ks) {                                      \
            const int p_ = ks >> 1, kk_ = ks & 1;                              \
            s16x8 af[4], bf[4];                                                \
            _Pragma("unroll")                                                  \
            for (int mt = 0; mt < 4; ++mt) {                                   \
                const int s_ = p_ * 512 + kk_ * 256 + l4 * 64 + mt * 16 + l15; \
                af[mt] = *(const s16x8*)&S[(s_ ^ (4 * kk_ + l4)) * 8];         \
            }                                                                  \
            _Pragma("unroll")                                                  \
            for (int nt = 0; nt < 4; ++nt)                                     \
                bf[nt] = *(const s16x8*)((WFM) +                               \
                         ((size_t)((wv * 4 + nt) * 16 + ks) * 64 + lane) * 8); \
            _Pragma("unroll")                                                  \
            for (int mt = 0; mt < 4; ++mt)                                     \
                _Pragma("unroll")                                              \
                for (int nt = 0; nt < 4; ++nt)                                 \
                    acc[mt][nt] = mma(af[mt], bf[nt], acc[mt][nt]);            \
        }                                                                      \
    }

    // ---------------- stage C ----------------
    STAGE(csrc);
    __syncthreads();

    // ---------------- GEMM-C ----------------
#pragma unroll
    for (int x = 0; x < 4; ++x)
#pragma unroll
        for (int y = 0; y < 4; ++y) acc[x][y] = fz;
    GEMM16(wf + 262144);
    __syncthreads();   // S (C data) dead -> tail tiles may land

    // Cp + bias -> T ; cb frags (Cp^T as B operand: contiguous rows)
#pragma unroll
    for (int nt = 0; nt < 4; ++nt) {
        float bcv = bc[wv * 64 + nt * 16 + l15];
#pragma unroll
        for (int mt = 0; mt < 4; ++mt)
#pragma unroll
            for (int r = 0; r < 4; ++r)
                Tw[TS(mt * 16 + l4 * 4 + r, nt * 16 + l15)] = f2bf(acc[mt][nt][r] + bcv);
    }
    LDS_FENCE();   // cross-lane: cb reads other lanes' Cp writes
    s16x8 cb[4][2];
#pragma unroll
    for (int nt = 0; nt < 4; ++nt)
#pragma unroll
        for (int ks = 0; ks < 2; ++ks)
            cb[nt][ks] = *(const s16x8*)&Tw[TS(nt * 16 + l15, ks * 32 + l4 * 8)];
    __syncthreads();   // all waves extracted cb -> T region may be overwritten

    // ---------------- stage Q (same buffer; cb safely in regs) ----------------
    STAGE(qsrc);
    __syncthreads();

    // ---------------- GEMM-Q (same acc regs) ----------------
#pragma unroll
    for (int x = 0; x < 4; ++x)
#pragma unroll
        for (int y = 0; y < 4; ++y) acc[x][y] = fz;
    GEMM16(wf);
    __syncthreads();   // S (Q data) dead -> tail tiles may land

    // Qp + bias -> T ; qa/qb frags
#pragma unroll
    for (int nt = 0; nt < 4; ++nt) {
        float bqv = bq[wv * 64 + nt * 16 + l15];
#pragma unroll
        for (int mt = 0; mt < 4; ++mt)
#pragma unroll
            for (int r = 0; r < 4; ++r)
                Tw[TS(mt * 16 + l4 * 4 + r, nt * 16 + l15)] = f2bf(acc[mt][nt][r] + bqv);
    }
    LDS_FENCE();   // cross-lane: qa/qb read other lanes' Qp writes
    s16x8 qa[4][2], qb[4][2];
#pragma unroll
    for (int mt = 0; mt < 4; ++mt)
#pragma unroll
        for (int ks = 0; ks < 2; ++ks)
            qa[mt][ks] = *(const s16x8*)&Tw[TS(mt * 16 + l15, ks * 32 + l4 * 8)];
#pragma unroll
    for (int nt = 0; nt < 4; ++nt)
#pragma unroll
        for (int ks = 0; ks < 2; ++ks) {
            s16x8 v;
#pragma unroll
            for (int j = 0; j < 8; ++j)
                v[j] = (short)Tw[TS(ks * 32 + l4 * 8 + j, nt * 16 + l15)];
            qb[nt][ks] = v;
        }

    // ---------------- attention tail (R3/R13 algebra, XOR T) ----------------
    f32x4 Sc[4][4];
#pragma unroll
    for (int x = 0; x < 4; ++x)
#pragma unroll
        for (int y = 0; y < 4; ++y) Sc[x][y] = fz;
#pragma unroll
    for (int ks = 0; ks < 2; ++ks)
#pragma unroll
        for (int mt = 0; mt < 4; ++mt)
#pragma unroll
            for (int nt = 0; nt < 4; ++nt)
                Sc[mt][nt] = mma(qa[mt][ks], cb[nt][ks], Sc[mt][nt]);

    // softmax over keys (rows): P1 -> T
#pragma unroll
    for (int mt = 0; mt < 4; ++mt)
#pragma unroll
        for (int r = 0; r < 4; ++r) {
            float m = fmaxf(fmaxf(Sc[mt][0][r], Sc[mt][1][r]),
                            fmaxf(Sc[mt][2][r], Sc[mt][3][r]));
            m = fmaxf(m, __shfl_xor(m, 1));
            m = fmaxf(m, __shfl_xor(m, 2));
            m = fmaxf(m, __shfl_xor(m, 4));
            m = fmaxf(m, __shfl_xor(m, 8));
            float e[4], s = 0.f;
#pragma unroll
            for (int nt = 0; nt < 4; ++nt) { e[nt] = __expf(SCALE * (Sc[mt][nt][r] - m)); s += e[nt]; }
            s += __shfl_xor(s, 1);
            s += __shfl_xor(s, 2);
            s += __shfl_xor(s, 4);
            s += __shfl_xor(s, 8);
            float inv = 1.f / s;
            int r3 = mt * 16 + l4 * 4 + r;
#pragma unroll
            for (int nt = 0; nt < 4; ++nt)
                Tw[TS(r3, nt * 16 + l15)] = f2bf(e[nt] * inv);
        }
    LDS_FENCE();   // cross-lane: pa reads other lanes' P1 writes

    s16x8 pa[4][2];
#pragma unroll
    for (int mt = 0; mt < 4; ++mt)
#pragma unroll
        for (int ks = 0; ks < 2; ++ks)
            pa[mt][ks] = *(const s16x8*)&Tw[TS(mt * 16 + l15, ks * 32 + l4 * 8)];

    // softmax over queries (cols): P2^T -> T
#pragma unroll
    for (int nt = 0; nt < 4; ++nt) {
        float m = -1e30f;
#pragma unroll
        for (int mt = 0; mt < 4; ++mt)
#pragma unroll
            for (int r = 0; r < 4; ++r) m = fmaxf(m, Sc[mt][nt][r]);
        m = fmaxf(m, __shfl_xor(m, 16));
        m = fmaxf(m, __shfl_xor(m, 32));
        float ee[4][4], s = 0.f;
#pragma unroll
        for (int mt = 0; mt < 4; ++mt)
#pragma unroll
            for (int r = 0; r < 4; ++r) { ee[mt][r] = __expf(SCALE * (Sc[mt][nt][r] - m)); s += ee[mt][r]; }
        s += __shfl_xor(s, 16);
        s += __shfl_xor(s, 32);
        float inv = 1.f / s;
        int krow = nt * 16 + l15;
#pragma unroll
        for (int mt = 0; mt < 4; ++mt)
#pragma unroll
            for (int r = 0; r < 4; ++r)
                Tw[TS(krow, mt * 16 + l4 * 4 + r)] = f2bf(ee[mt][r] * inv);
    }
    LDS_FENCE();   // cross-lane: p2a reads other lanes' P2^T writes

    // c_coattn = P1 @ Cp^T ; store
    f32x4 O[4][4];
#pragma unroll
    for (int x = 0; x < 4; ++x)
#pragma unroll
        for (int y = 0; y < 4; ++y) O[x][y] = fz;
#pragma unroll
    for (int ks = 0; ks < 2; ++ks)
#pragma unroll
        for (int mt = 0; mt < 4; ++mt)
#pragma unroll
            for (int nt = 0; nt < 4; ++nt)
                O[mt][nt] = mma(pa[mt][ks], cb[nt][ks], O[mt][nt]);

    float* cO = out;
#pragma unroll
    for (int mt = 0; mt < 4; ++mt)
#pragma unroll
        for (int nt = 0; nt < 4; ++nt)
#pragma unroll
            for (int r = 0; r < 4; ++r) {
                int qrow = mt * 16 + l4 * 4 + r;
                cO[((size_t)b * SEQ + qrow) * (NH * 64) + wv * 64 + nt * 16 + l15] = O[mt][nt][r];
            }

    // q_coattn = P2^T @ Qp ; store
    s16x8 p2a[4][2];
#pragma unroll
    for (int mt = 0; mt < 4; ++mt)
#pragma unroll
        for (int ks = 0; ks < 2; ++ks)
            p2a[mt][ks] = *(const s16x8*)&Tw[TS(mt * 16 + l15, ks * 32 + l4 * 8)];

#pragma unroll
    for (int x = 0; x < 4; ++x)
#pragma unroll
        for (int y = 0; y < 4; ++y) O[x][y] = fz;
#pragma unroll
    for (int ks = 0; ks < 2; ++ks)
#pragma unroll
        for (int mt = 0; mt < 4; ++mt)
#pragma unroll
            for (int nt = 0; nt < 4; ++nt)
                O[mt][nt] = mma(p2a[mt][ks], qb[nt][ks], O[mt][nt]);

    float* qO = out + (size_t)NB * SEQ * NH * 64;
#pragma unroll
    for (int mt = 0; mt < 4; ++mt)
#pragma unroll
        for (int nt = 0; nt < 4; ++nt)
#pragma unroll
            for (int r = 0; r < 4; ++r) {
                int krow = mt * 16 + l4 * 4 + r;
                qO[((size_t)b * SEQ + krow) * (NH * 64) + wv * 64 + nt * 16 + l15] = O[mt][nt][r];
            }

#undef STAGE
#undef GEMM16
}

extern "C" void kernel_launch(void* const* d_in, const int* in_sizes, int n_in,
                              void* d_out, int out_size, void* d_ws, size_t ws_size,
                              hipStream_t stream) {
    const float* query   = (const float*)d_in[0];
    const float* context = (const float*)d_in[1];
    const float* Wq      = (const float*)d_in[2];
    const float* bq      = (const float*)d_in[3];
    const float* Wc      = (const float*)d_in[4];
    const float* bc      = (const float*)d_in[5];
    float* out = (float*)d_out;

    unsigned short* wfrag = (unsigned short*)d_ws;   // 1 MB bf16 weight frags

    prep_weights<<<256, 256, 0, stream>>>(Wq, Wc, wfrag);
    fused_s<<<NB, 512, 0, stream>>>(query, context, bq, bc, wfrag, out);
}